// Round 1
// baseline (787.250 us; speedup 1.0000x reference)
//
#include <hip/hip_runtime.h>
#include <math.h>

// GaussianSampleST fused kernel (fp32)
// x:(16,64,30,64,44)  out:(16,64,30,48,22)
// Block = (n, t_out, channel-group-of-8); grid = 16*30*8 = 3840, 256 threads.
// LDS cut to 38KB (t2s pipelined over h-halves) -> 4 blocks/CU, 4 waves/SIMD.

#define EPS_ 1e-8f

__global__ __launch_bounds__(256, 4) void gst_kernel(
    const float* __restrict__ x,
    const float* __restrict__ dx,  const float* __restrict__ dy,
    const float* __restrict__ ls2, const float* __restrict__ ld,
    const float* __restrict__ lg,
    const float* __restrict__ dtp, const float* __restrict__ ldt,
    const float* __restrict__ lgt,
    float* __restrict__ out)
{
    __shared__ float FyT[64][36];     // [h][i]   (Fy row-normalized, pre-scaled by Ws*gamma)
    __shared__ float FxT[44][24];     // [w][j]   (Fx row-normalized)
    __shared__ float t2s[8][32][24];  // [c][h-local][j] staging, one h-half at a time

    const int tid = threadIdx.x;
    int b = blockIdx.x;
    const int cg = b & 7; b >>= 3;
    const int tq = b % 30;
    const int n  = b / 30;

    // ---- temporal interpolation params (block-uniform) ----
    const float dtv     = tanhf(dtp[n]) * 15.f + 15.f;
    const float delta_t = expf(ldt[n]);
    const float gamma_t = 1.f / (1.f + expf(-lgt[n]));
    float mu_t = dtv + ((float)tq - 15.f) * delta_t;
    mu_t = mu_t / 29.f * 2.f - 1.f;
    const float iy  = ((mu_t + 1.f) * 30.f - 1.f) * 0.5f;
    const float iy0 = floorf(iy);
    const float w1  = iy - iy0;
    const int   i0  = (int)iy0;
    const int   i1  = i0 + 1;
    const float W0 = (i0 >= 0 && i0 < 30) ? 0.5f * gamma_t * (1.f - w1) : 0.f;
    const float W1 = (i1 >= 0 && i1 < 30) ? 0.5f * gamma_t * w1 : 0.f;
    const int t0 = min(max(i0, 0), 29);
    const int t1 = min(max(i1, 0), 29);

    // thread mappings
    const int c_loc = tid >> 5;        // 0..7   (both GEMMs)
    const int hp    = tid & 31;        // GEMM1: local h-row
    const int jt    = tid & 3;         // GEMM2: j-tile base 6*jt
    const int it    = (tid >> 2) & 7;  // GEMM2: i-tile base 4*it
    const int j0    = 6 * jt;
    const int i0r   = 4 * it;

    float acc2[4][6];
#pragma unroll
    for (int r = 0; r < 4; ++r)
#pragma unroll
        for (int s2 = 0; s2 < 6; ++s2) acc2[r][s2] = 0.f;

    bool first = true;
#pragma unroll 1
    for (int s = 0; s < 2; ++s) {
        const float Ws = s ? W1 : W0;
        const int   ts = s ? t1 : t0;
        if (Ws == 0.f) continue;          // block-uniform branch
        if (!first) __syncthreads();      // protect LDS reuse from previous source
        first = false;

        // ---- per-source attention params into LDS (all 256 lanes) ----
        const int nt = n * 30 + ts;
        const float sigma2 = expf(ls2[nt]);
        const float inv2s2 = 0.5f / sigma2;
        const float delta  = expf(ld[nt]);
        const float gamma  = 1.f / (1.f + expf(-lg[nt]));
        const float A      = Ws * gamma;

        if (tid < 128) {
            // Fy: row i = tid>>2 (0..31), quarter q = tid&3 covers h = 16q..16q+15
            const int i = tid >> 2, q = tid & 3;
            float pod = dy[nt] + 0.5f * (ts >= 1 ? dy[nt - 1] : 0.f)
                               + 0.5f * (ts >= 2 ? dy[nt - 2] : 0.f);
            const float mu = tanhf(pod) * 32.f + 32.f + ((float)i - 16.f) * delta;
            float e[16];
            float sum = 0.f;
#pragma unroll
            for (int k = 0; k < 16; ++k) {
                const float d = (float)(16 * q + k) - mu;
                e[k] = expf(-d * d * inv2s2);
                sum += e[k];
            }
            sum += __shfl_xor(sum, 1);
            sum += __shfl_xor(sum, 2);
            const float sc = A / fmaxf(sum, EPS_);
#pragma unroll
            for (int k = 0; k < 16; ++k)
                FyT[16 * q + k][i] = e[k] * sc;
        } else {
            // Fx: row j = (tid-128)>>2 (0..31, active j<22), quarter q covers w = 11q..11q+10
            const int tx = tid - 128;
            const int j = tx >> 2, q = tx & 3;
            float pod = dx[nt] + 0.5f * (ts >= 1 ? dx[nt - 1] : 0.f)
                               + 0.5f * (ts >= 2 ? dx[nt - 2] : 0.f);
            const float mu = tanhf(pod) * 22.f + 22.f + ((float)j - 11.f) * delta;
            float e[11];
            float sum = 0.f;
#pragma unroll
            for (int m = 0; m < 11; ++m) {
                const float d = (float)(11 * q + m) - mu;
                e[m] = expf(-d * d * inv2s2);
                sum += e[m];
            }
            sum += __shfl_xor(sum, 1);
            sum += __shfl_xor(sum, 2);
            const float sc = 1.f / fmaxf(sum, EPS_);
            if (j < 22) {
#pragma unroll
                for (int m = 0; m < 11; ++m)
                    FxT[11 * q + m][j] = e[m] * sc;
            }
        }
        __syncthreads();

        // ---- pipelined over h-halves: GEMM1 fills t2s, GEMM2 accumulates ----
#pragma unroll 1
        for (int hc = 0; hc < 2; ++hc) {
            // GEMM1: t2s[c][hp][j] = sum_w X[c][32*hc+hp][w] * FxT[w][j]
            {
                const size_t xoff =
                    ((((size_t)n * 64 + (size_t)(cg * 8 + c_loc)) * 30
                      + (size_t)ts) * 64 + (size_t)(32 * hc + hp)) * 44;
                const float4* xr = reinterpret_cast<const float4*>(x + xoff);
                float4 xv[11];
#pragma unroll
                for (int wi = 0; wi < 11; ++wi) xv[wi] = xr[wi];

                float a0[22];
#pragma unroll
                for (int j = 0; j < 22; ++j) a0[j] = 0.f;

#pragma unroll
                for (int wi = 0; wi < 11; ++wi) {
                    const float xav[4] = { xv[wi].x, xv[wi].y, xv[wi].z, xv[wi].w };
#pragma unroll
                    for (int k = 0; k < 4; ++k) {
                        const float4* fxr =
                            reinterpret_cast<const float4*>(&FxT[4 * wi + k][0]);
                        const float4 f0 = fxr[0], f1 = fxr[1], f2 = fxr[2],
                                     f3 = fxr[3], f4 = fxr[4];
                        const float2 f5 =
                            *reinterpret_cast<const float2*>(&FxT[4 * wi + k][20]);
                        const float fv[22] = { f0.x, f0.y, f0.z, f0.w,
                                               f1.x, f1.y, f1.z, f1.w,
                                               f2.x, f2.y, f2.z, f2.w,
                                               f3.x, f3.y, f3.z, f3.w,
                                               f4.x, f4.y, f4.z, f4.w,
                                               f5.x, f5.y };
                        const float va = xav[k];
#pragma unroll
                        for (int j = 0; j < 22; ++j) a0[j] += va * fv[j];
                    }
                }
                float4* d0 = reinterpret_cast<float4*>(&t2s[c_loc][hp][0]);
                d0[0] = make_float4(a0[0],  a0[1],  a0[2],  a0[3]);
                d0[1] = make_float4(a0[4],  a0[5],  a0[6],  a0[7]);
                d0[2] = make_float4(a0[8],  a0[9],  a0[10], a0[11]);
                d0[3] = make_float4(a0[12], a0[13], a0[14], a0[15]);
                d0[4] = make_float4(a0[16], a0[17], a0[18], a0[19]);
                d0[5] = make_float4(a0[20], a0[21], 0.f, 0.f);
            }
            __syncthreads();

            // GEMM2: acc2[r][s2] += sum_hp FyT[32*hc+hp][i0r+r] * t2s[c][hp][j0+s2]
            {
#pragma unroll 4
                for (int hp2 = 0; hp2 < 32; ++hp2) {
                    const float4 fy =
                        *reinterpret_cast<const float4*>(&FyT[32 * hc + hp2][i0r]);
                    const float2* tp =
                        reinterpret_cast<const float2*>(&t2s[c_loc][hp2][j0]);
                    const float2 q0 = tp[0], q1 = tp[1], q2 = tp[2];
                    const float fyv[4] = { fy.x, fy.y, fy.z, fy.w };
                    const float tv[6]  = { q0.x, q0.y, q1.x, q1.y, q2.x, q2.y };
#pragma unroll
                    for (int r = 0; r < 4; ++r)
#pragma unroll
                        for (int s2 = 0; s2 < 6; ++s2)
                            acc2[r][s2] += fyv[r] * tv[s2];
                }
            }
            if (hc == 0) __syncthreads();   // t2s about to be overwritten by next half
        }
    }

    // ---- store: out[n][c][tq][i'][j], rows 0..7 and 40..47 are zero-pad ----
    const size_t ob =
        (((size_t)n * 64 + (size_t)(cg * 8)) * 30 + (size_t)tq) * 1056;

    // zero the 16 pad rows for this block's 8 channels
    for (int idx = tid; idx < 8 * 16 * 22; idx += 256) {
        const int c   = idx / 352;
        const int rem = idx % 352;
        const int r   = rem / 22;
        const int j   = rem % 22;
        const int ip  = (r < 8) ? r : (r + 32);
        out[ob + (size_t)c * 31680 + (size_t)(ip * 22 + j)] = 0.f;
    }

    // main 32 rows
#pragma unroll
    for (int r = 0; r < 4; ++r) {
#pragma unroll
        for (int s2 = 0; s2 < 6; ++s2) {
            const int j = j0 + s2;
            if (j < 22) {
                out[ob + (size_t)c_loc * 31680
                       + (size_t)((8 + i0r + r) * 22 + j)] = acc2[r][s2];
            }
        }
    }
}

extern "C" void kernel_launch(void* const* d_in, const int* in_sizes, int n_in,
                              void* d_out, int out_size, void* d_ws, size_t ws_size,
                              hipStream_t stream) {
    const float* x   = (const float*)d_in[0];
    const float* dx  = (const float*)d_in[1];
    const float* dy  = (const float*)d_in[2];
    const float* ls2 = (const float*)d_in[3];
    const float* ld  = (const float*)d_in[4];
    const float* lg  = (const float*)d_in[5];
    const float* dtp = (const float*)d_in[6];
    const float* ldt = (const float*)d_in[7];
    const float* lgt = (const float*)d_in[8];
    float* out = (float*)d_out;

    dim3 grid(16 * 30 * 8), block(256);
    hipLaunchKernelGGL(gst_kernel, grid, block, 0, stream,
                       x, dx, dy, ls2, ld, lg, dtp, ldt, lgt, out);
}

// Round 3
// 643.889 us; speedup vs baseline: 1.2226x; 1.2226x over previous
//
#include <hip/hip_runtime.h>
#include <math.h>

// GaussianSampleST fused kernel (fp32)
// x:(16,64,30,64,44)  out:(16,64,30,48,22)
// Block = (n, t_out, channel-group-of-8); grid = 16*30*8 = 3840, 256 threads.
// LDS = 39,040 B -> 4 blocks/CU.  GEMM1: 128 threads x 2 h-rows (FxT reads
// amortized).  t2s stride 26 floats + b64 access -> conflict-free stores.
// (Resubmit of round-2 kernel: previous run was an infra failure, not a
// kernel verdict.)

#define EPS_ 1e-8f

__global__ __launch_bounds__(256) void gst_kernel(
    const float* __restrict__ x,
    const float* __restrict__ dx,  const float* __restrict__ dy,
    const float* __restrict__ ls2, const float* __restrict__ ld,
    const float* __restrict__ lg,
    const float* __restrict__ dtp, const float* __restrict__ ldt,
    const float* __restrict__ lgt,
    float* __restrict__ out)
{
    __shared__ float FyT[64][32];     // [h][i]   (Fy, pre-scaled by Ws*gamma)
    __shared__ float FxT[44][24];     // [w][j]   (Fx row-normalized)
    __shared__ float t2s[8][32][26];  // [c][h-local][j], stride 26 => conflict-free b64

    const int tid = threadIdx.x;
    int b = blockIdx.x;
    const int cg = b & 7; b >>= 3;
    const int tq = b % 30;
    const int n  = b / 30;

    // ---- temporal interpolation params (block-uniform) ----
    const float dtv     = tanhf(dtp[n]) * 15.f + 15.f;
    const float delta_t = expf(ldt[n]);
    const float gamma_t = 1.f / (1.f + expf(-lgt[n]));
    float mu_t = dtv + ((float)tq - 15.f) * delta_t;
    mu_t = mu_t / 29.f * 2.f - 1.f;
    const float iy  = ((mu_t + 1.f) * 30.f - 1.f) * 0.5f;
    const float iy0 = floorf(iy);
    const float w1  = iy - iy0;
    const int   i0  = (int)iy0;
    const int   i1  = i0 + 1;
    const float W0 = (i0 >= 0 && i0 < 30) ? 0.5f * gamma_t * (1.f - w1) : 0.f;
    const float W1 = (i1 >= 0 && i1 < 30) ? 0.5f * gamma_t * w1 : 0.f;
    const int t0 = min(max(i0, 0), 29);
    const int t1 = min(max(i1, 0), 29);

    // GEMM2 mapping (all 256 threads)
    const int c_loc = tid >> 5;        // 0..7
    const int jt    = tid & 3;         // j-tile base 6*jt
    const int it    = (tid >> 2) & 7;  // i-tile base 4*it
    const int j0    = 6 * jt;
    const int i0r   = 4 * it;

    // GEMM1 mapping (tid < 128): 2 rows per thread: hl and hl+16 (of the 32-row half)
    const int c1 = tid >> 4;           // 0..7
    const int hl = tid & 15;           // 0..15

    float acc2[4][6];
#pragma unroll
    for (int r = 0; r < 4; ++r)
#pragma unroll
        for (int s2 = 0; s2 < 6; ++s2) acc2[r][s2] = 0.f;

    bool first = true;
#pragma unroll 1
    for (int s = 0; s < 2; ++s) {
        const float Ws = s ? W1 : W0;
        const int   ts = s ? t1 : t0;
        if (Ws == 0.f) continue;          // block-uniform branch
        if (!first) __syncthreads();      // protect FyT/FxT reuse from previous source
        first = false;

        // ---- per-source attention params into LDS (all 256 lanes) ----
        const int nt = n * 30 + ts;
        const float sigma2 = expf(ls2[nt]);
        const float inv2s2 = 0.5f / sigma2;
        const float delta  = expf(ld[nt]);
        const float gamma  = 1.f / (1.f + expf(-lg[nt]));
        const float A      = Ws * gamma;

        if (tid < 128) {
            // Fy: row i = tid>>2 (0..31), quarter q = tid&3 covers h = 16q..16q+15
            const int i = tid >> 2, q = tid & 3;
            float pod = dy[nt] + 0.5f * (ts >= 1 ? dy[nt - 1] : 0.f)
                               + 0.5f * (ts >= 2 ? dy[nt - 2] : 0.f);
            const float mu = tanhf(pod) * 32.f + 32.f + ((float)i - 16.f) * delta;
            float e[16];
            float sum = 0.f;
#pragma unroll
            for (int k = 0; k < 16; ++k) {
                const float d = (float)(16 * q + k) - mu;
                e[k] = expf(-d * d * inv2s2);
                sum += e[k];
            }
            sum += __shfl_xor(sum, 1);
            sum += __shfl_xor(sum, 2);
            const float sc = A / fmaxf(sum, EPS_);
#pragma unroll
            for (int k = 0; k < 16; ++k)
                FyT[16 * q + k][i] = e[k] * sc;
        } else {
            // Fx: row j = (tid-128)>>2, quarter q covers w = 11q..11q+10
            const int tx = tid - 128;
            const int j = tx >> 2, q = tx & 3;
            float pod = dx[nt] + 0.5f * (ts >= 1 ? dx[nt - 1] : 0.f)
                               + 0.5f * (ts >= 2 ? dx[nt - 2] : 0.f);
            const float mu = tanhf(pod) * 22.f + 22.f + ((float)j - 11.f) * delta;
            float e[11];
            float sum = 0.f;
#pragma unroll
            for (int m = 0; m < 11; ++m) {
                const float d = (float)(11 * q + m) - mu;
                e[m] = expf(-d * d * inv2s2);
                sum += e[m];
            }
            sum += __shfl_xor(sum, 1);
            sum += __shfl_xor(sum, 2);
            const float sc = 1.f / fmaxf(sum, EPS_);
            if (j < 22) {
#pragma unroll
                for (int m = 0; m < 11; ++m)
                    FxT[11 * q + m][j] = e[m] * sc;
            }
        }
        __syncthreads();

        // ---- pipelined over h-halves: GEMM1 fills t2s, GEMM2 accumulates ----
#pragma unroll 1
        for (int hc = 0; hc < 2; ++hc) {
            if (tid < 128) {
                // GEMM1: rows h = 32*hc + hl and 32*hc + hl + 16
                float a0[22], a1[22];
#pragma unroll
                for (int j = 0; j < 22; ++j) { a0[j] = 0.f; a1[j] = 0.f; }

                const size_t xoff =
                    ((((size_t)n * 64 + (size_t)(cg * 8 + c1)) * 30
                      + (size_t)ts) * 64 + (size_t)(32 * hc + hl)) * 44;
                const float4* xr0 = reinterpret_cast<const float4*>(x + xoff);
                const float4* xr1 = reinterpret_cast<const float4*>(x + xoff + 16 * 44);

#pragma unroll 2
                for (int wi = 0; wi < 11; ++wi) {
                    const float4 xa = xr0[wi];
                    const float4 xb = xr1[wi];
                    const float xav[4] = { xa.x, xa.y, xa.z, xa.w };
                    const float xbv[4] = { xb.x, xb.y, xb.z, xb.w };
#pragma unroll
                    for (int k = 0; k < 4; ++k) {
                        const float4* fxr =
                            reinterpret_cast<const float4*>(&FxT[4 * wi + k][0]);
                        const float4 f0 = fxr[0], f1 = fxr[1], f2 = fxr[2],
                                     f3 = fxr[3], f4 = fxr[4];
                        const float2 f5 =
                            *reinterpret_cast<const float2*>(&FxT[4 * wi + k][20]);
                        const float fv[22] = { f0.x, f0.y, f0.z, f0.w,
                                               f1.x, f1.y, f1.z, f1.w,
                                               f2.x, f2.y, f2.z, f2.w,
                                               f3.x, f3.y, f3.z, f3.w,
                                               f4.x, f4.y, f4.z, f4.w,
                                               f5.x, f5.y };
                        const float va = xav[k], vb = xbv[k];
#pragma unroll
                        for (int j = 0; j < 22; ++j) {
                            a0[j] += va * fv[j];
                            a1[j] += vb * fv[j];
                        }
                    }
                }
                // store rows as float2 (stride-26 rows: conflict-free b64)
                float2* d0 = reinterpret_cast<float2*>(&t2s[c1][hl][0]);
                float2* d1 = reinterpret_cast<float2*>(&t2s[c1][hl + 16][0]);
#pragma unroll
                for (int p = 0; p < 11; ++p) {
                    d0[p] = make_float2(a0[2 * p], a0[2 * p + 1]);
                    d1[p] = make_float2(a1[2 * p], a1[2 * p + 1]);
                }
                d0[11] = make_float2(0.f, 0.f);   // cols 22,23 read-safe
                d1[11] = make_float2(0.f, 0.f);
            }
            __syncthreads();

            // GEMM2: acc2[r][s2] += sum_hp FyT[32*hc+hp][i0r+r] * t2s[c][hp][j0+s2]
            {
#pragma unroll 4
                for (int hp2 = 0; hp2 < 32; ++hp2) {
                    const float4 fy =
                        *reinterpret_cast<const float4*>(&FyT[32 * hc + hp2][i0r]);
                    const float2* tp =
                        reinterpret_cast<const float2*>(&t2s[c_loc][hp2][j0]);
                    const float2 q0 = tp[0], q1 = tp[1], q2 = tp[2];
                    const float fyv[4] = { fy.x, fy.y, fy.z, fy.w };
                    const float tv[6]  = { q0.x, q0.y, q1.x, q1.y, q2.x, q2.y };
#pragma unroll
                    for (int r = 0; r < 4; ++r)
#pragma unroll
                        for (int s2 = 0; s2 < 6; ++s2)
                            acc2[r][s2] += fyv[r] * tv[s2];
                }
            }
            if (hc == 0) __syncthreads();   // t2s about to be overwritten
        }
    }

    // ---- store: out[n][c][tq][i'][j], rows 0..7 and 40..47 are zero-pad ----
    const size_t ob =
        (((size_t)n * 64 + (size_t)(cg * 8)) * 30 + (size_t)tq) * 1056;

    // zero the 16 pad rows for this block's 8 channels
    for (int idx = tid; idx < 8 * 16 * 22; idx += 256) {
        const int c   = idx / 352;
        const int rem = idx % 352;
        const int r   = rem / 22;
        const int j   = rem % 22;
        const int ip  = (r < 8) ? r : (r + 32);
        out[ob + (size_t)c * 31680 + (size_t)(ip * 22 + j)] = 0.f;
    }

    // main 32 rows
#pragma unroll
    for (int r = 0; r < 4; ++r) {
#pragma unroll
        for (int s2 = 0; s2 < 6; ++s2) {
            const int j = j0 + s2;
            if (j < 22) {
                out[ob + (size_t)c_loc * 31680
                       + (size_t)((8 + i0r + r) * 22 + j)] = acc2[r][s2];
            }
        }
    }
}

extern "C" void kernel_launch(void* const* d_in, const int* in_sizes, int n_in,
                              void* d_out, int out_size, void* d_ws, size_t ws_size,
                              hipStream_t stream) {
    const float* x   = (const float*)d_in[0];
    const float* dx  = (const float*)d_in[1];
    const float* dy  = (const float*)d_in[2];
    const float* ls2 = (const float*)d_in[3];
    const float* ld  = (const float*)d_in[4];
    const float* lg  = (const float*)d_in[5];
    const float* dtp = (const float*)d_in[6];
    const float* ldt = (const float*)d_in[7];
    const float* lgt = (const float*)d_in[8];
    float* out = (float*)d_out;

    dim3 grid(16 * 30 * 8), block(256);
    hipLaunchKernelGGL(gst_kernel, grid, block, 0, stream,
                       x, dx, dy, ls2, ld, lg, dtp, ldt, lgt, out);
}

// Round 4
// 624.569 us; speedup vs baseline: 1.2605x; 1.0309x over previous
//
#include <hip/hip_runtime.h>
#include <math.h>

// GaussianSampleST fused kernel (fp32)
// x:(16,64,30,64,44)  out:(16,64,30,48,22)
// Block = (n, t_out, channel-group-of-8); grid = 16*30*8 = 3840, 256 threads.
// LDS = 39,040 B.  GEMM1: ALL 256 threads, 2 rows each = one row per h-half
// (h=hl and h=32+hl) in a single FxT streaming pass; half-1 result kept in
// registers while GEMM2 consumes half-0 from t2s.  t2s stride 26 -> b64
// conflict-free.  No wave idles during GEMM1 (round-3's tid<128 starved
// half the wave slots: VALUBusy 31%).

#define EPS_ 1e-8f

__global__ __launch_bounds__(256) void gst_kernel(
    const float* __restrict__ x,
    const float* __restrict__ dx,  const float* __restrict__ dy,
    const float* __restrict__ ls2, const float* __restrict__ ld,
    const float* __restrict__ lg,
    const float* __restrict__ dtp, const float* __restrict__ ldt,
    const float* __restrict__ lgt,
    float* __restrict__ out)
{
    __shared__ float FyT[64][32];     // [h][i]   (Fy, pre-scaled by Ws*gamma)
    __shared__ float FxT[44][24];     // [w][j]   (Fx row-normalized, cols 22/23 = 0)
    __shared__ float t2s[8][32][26];  // [c][h-in-half][j], stride 26

    const int tid = threadIdx.x;
    int b = blockIdx.x;
    const int cg = b & 7; b >>= 3;
    const int tq = b % 30;
    const int n  = b / 30;

    // ---- temporal interpolation params (block-uniform) ----
    const float dtv     = tanhf(dtp[n]) * 15.f + 15.f;
    const float delta_t = expf(ldt[n]);
    const float gamma_t = 1.f / (1.f + expf(-lgt[n]));
    float mu_t = dtv + ((float)tq - 15.f) * delta_t;
    mu_t = mu_t / 29.f * 2.f - 1.f;
    const float iy  = ((mu_t + 1.f) * 30.f - 1.f) * 0.5f;
    const float iy0 = floorf(iy);
    const float w1  = iy - iy0;
    const int   i0  = (int)iy0;
    const int   i1  = i0 + 1;
    const float W0 = (i0 >= 0 && i0 < 30) ? 0.5f * gamma_t * (1.f - w1) : 0.f;
    const float W1 = (i1 >= 0 && i1 < 30) ? 0.5f * gamma_t * w1 : 0.f;
    const int t0 = min(max(i0, 0), 29);
    const int t1 = min(max(i1, 0), 29);

    // shared thread mapping: c = tid>>5 for both GEMMs
    const int c_loc = tid >> 5;        // 0..7
    const int hl    = tid & 31;        // GEMM1: rows h=hl and h=32+hl
    const int jt    = tid & 3;         // GEMM2: j-tile base 6*jt
    const int it    = (tid >> 2) & 7;  // GEMM2: i-tile base 4*it
    const int j0    = 6 * jt;
    const int i0r   = 4 * it;

    // ---- store zero pad rows early (independent of compute) ----
    const size_t ob =
        (((size_t)n * 64 + (size_t)(cg * 8)) * 30 + (size_t)tq) * 1056;
    for (int idx = tid; idx < 8 * 16 * 22; idx += 256) {
        const int c   = idx / 352;
        const int rem = idx % 352;
        const int r   = rem / 22;
        const int j   = rem % 22;
        const int ip  = (r < 8) ? r : (r + 32);
        out[ob + (size_t)c * 31680 + (size_t)(ip * 22 + j)] = 0.f;
    }

    float acc2[4][6];
#pragma unroll
    for (int r = 0; r < 4; ++r)
#pragma unroll
        for (int s2 = 0; s2 < 6; ++s2) acc2[r][s2] = 0.f;

    bool first = true;
#pragma unroll 1
    for (int s = 0; s < 2; ++s) {
        const float Ws = s ? W1 : W0;
        const int   ts = s ? t1 : t0;
        if (Ws == 0.f) continue;          // block-uniform branch
        if (!first) __syncthreads();      // protect LDS reuse from previous source
        first = false;

        // ---- per-source attention params into LDS (all 256 lanes) ----
        const int nt = n * 30 + ts;
        const float sigma2 = expf(ls2[nt]);
        const float inv2s2 = 0.5f / sigma2;
        const float delta  = expf(ld[nt]);
        const float gamma  = 1.f / (1.f + expf(-lg[nt]));
        const float A      = Ws * gamma;

        if (tid < 128) {
            // Fy: row i = tid>>2 (0..31), quarter q = tid&3 covers h = 16q..16q+15
            const int i = tid >> 2, q = tid & 3;
            float pod = dy[nt] + 0.5f * (ts >= 1 ? dy[nt - 1] : 0.f)
                               + 0.5f * (ts >= 2 ? dy[nt - 2] : 0.f);
            const float mu = tanhf(pod) * 32.f + 32.f + ((float)i - 16.f) * delta;
            float e[16];
            float sum = 0.f;
#pragma unroll
            for (int k = 0; k < 16; ++k) {
                const float d = (float)(16 * q + k) - mu;
                e[k] = expf(-d * d * inv2s2);
                sum += e[k];
            }
            sum += __shfl_xor(sum, 1);
            sum += __shfl_xor(sum, 2);
            const float sc = A / fmaxf(sum, EPS_);
#pragma unroll
            for (int k = 0; k < 16; ++k)
                FyT[16 * q + k][i] = e[k] * sc;
        } else {
            // Fx: row j = (tid-128)>>2, quarter q covers w = 11q..11q+10
            const int tx = tid - 128;
            const int j = tx >> 2, q = tx & 3;
            float pod = dx[nt] + 0.5f * (ts >= 1 ? dx[nt - 1] : 0.f)
                               + 0.5f * (ts >= 2 ? dx[nt - 2] : 0.f);
            const float mu = tanhf(pod) * 22.f + 22.f + ((float)j - 11.f) * delta;
            float e[11];
            float sum = 0.f;
#pragma unroll
            for (int m = 0; m < 11; ++m) {
                const float d = (float)(11 * q + m) - mu;
                e[m] = expf(-d * d * inv2s2);
                sum += e[m];
            }
            sum += __shfl_xor(sum, 1);
            sum += __shfl_xor(sum, 2);
            const float sc = 1.f / fmaxf(sum, EPS_);
            if (j < 22) {
#pragma unroll
                for (int m = 0; m < 11; ++m)
                    FxT[11 * q + m][j] = e[m] * sc;
            }
            // zero pad cols 22,23 (rows covered by q==3 lanes of each j group)
            if (j < 22 && q == 3) { /* nothing extra */ }
        }
        // zero FxT pad cols once (rows 0..43, cols 22..23): 88 cells by 88 lanes
        if (tid < 88) {
            FxT[tid >> 1][22 + (tid & 1)] = 0.f;
        }
        __syncthreads();

        // ---- GEMM1 (all 256 threads): rows h=hl (half0 -> a0), h=32+hl (half1 -> a1)
        float a0[22], a1[22];
#pragma unroll
        for (int j = 0; j < 22; ++j) { a0[j] = 0.f; a1[j] = 0.f; }
        {
            const size_t xoff =
                ((((size_t)n * 64 + (size_t)(cg * 8 + c_loc)) * 30
                  + (size_t)ts) * 64 + (size_t)hl) * 44;
            const float4* xr0 = reinterpret_cast<const float4*>(x + xoff);
            const float4* xr1 = reinterpret_cast<const float4*>(x + xoff + 32 * 44);

#pragma unroll 2
            for (int wi = 0; wi < 11; ++wi) {
                const float4 xa = xr0[wi];
                const float4 xb = xr1[wi];
                const float xav[4] = { xa.x, xa.y, xa.z, xa.w };
                const float xbv[4] = { xb.x, xb.y, xb.z, xb.w };
#pragma unroll
                for (int k = 0; k < 4; ++k) {
                    const float4* fxr =
                        reinterpret_cast<const float4*>(&FxT[4 * wi + k][0]);
                    const float4 f0 = fxr[0], f1 = fxr[1], f2 = fxr[2],
                                 f3 = fxr[3], f4 = fxr[4];
                    const float2 f5 =
                        *reinterpret_cast<const float2*>(&FxT[4 * wi + k][20]);
                    const float fv[22] = { f0.x, f0.y, f0.z, f0.w,
                                           f1.x, f1.y, f1.z, f1.w,
                                           f2.x, f2.y, f2.z, f2.w,
                                           f3.x, f3.y, f3.z, f3.w,
                                           f4.x, f4.y, f4.z, f4.w,
                                           f5.x, f5.y };
                    const float va = xav[k], vb = xbv[k];
#pragma unroll
                    for (int j = 0; j < 22; ++j) {
                        a0[j] += va * fv[j];
                        a1[j] += vb * fv[j];
                    }
                }
            }
        }

        // ---- half 0: store a0, consume via GEMM2 ----
        {
            float2* d0 = reinterpret_cast<float2*>(&t2s[c_loc][hl][0]);
#pragma unroll
            for (int p = 0; p < 11; ++p)
                d0[p] = make_float2(a0[2 * p], a0[2 * p + 1]);
            d0[11] = make_float2(0.f, 0.f);   // cols 22,23 read-safe
        }
        __syncthreads();
        {
#pragma unroll 4
            for (int hp2 = 0; hp2 < 32; ++hp2) {
                const float4 fy =
                    *reinterpret_cast<const float4*>(&FyT[hp2][i0r]);
                const float2* tp =
                    reinterpret_cast<const float2*>(&t2s[c_loc][hp2][j0]);
                const float2 q0 = tp[0], q1 = tp[1], q2 = tp[2];
                const float fyv[4] = { fy.x, fy.y, fy.z, fy.w };
                const float tv[6]  = { q0.x, q0.y, q1.x, q1.y, q2.x, q2.y };
#pragma unroll
                for (int r = 0; r < 4; ++r)
#pragma unroll
                    for (int s2 = 0; s2 < 6; ++s2)
                        acc2[r][s2] += fyv[r] * tv[s2];
            }
        }
        __syncthreads();

        // ---- half 1: store a1, consume via GEMM2 ----
        {
            float2* d1 = reinterpret_cast<float2*>(&t2s[c_loc][hl][0]);
#pragma unroll
            for (int p = 0; p < 11; ++p)
                d1[p] = make_float2(a1[2 * p], a1[2 * p + 1]);
            d1[11] = make_float2(0.f, 0.f);
        }
        __syncthreads();
        {
#pragma unroll 4
            for (int hp2 = 0; hp2 < 32; ++hp2) {
                const float4 fy =
                    *reinterpret_cast<const float4*>(&FyT[32 + hp2][i0r]);
                const float2* tp =
                    reinterpret_cast<const float2*>(&t2s[c_loc][hp2][j0]);
                const float2 q0 = tp[0], q1 = tp[1], q2 = tp[2];
                const float fyv[4] = { fy.x, fy.y, fy.z, fy.w };
                const float tv[6]  = { q0.x, q0.y, q1.x, q1.y, q2.x, q2.y };
#pragma unroll
                for (int r = 0; r < 4; ++r)
#pragma unroll
                    for (int s2 = 0; s2 < 6; ++s2)
                        acc2[r][s2] += fyv[r] * tv[s2];
            }
        }
    }

    // ---- store main 32 rows ----
#pragma unroll
    for (int r = 0; r < 4; ++r) {
#pragma unroll
        for (int s2 = 0; s2 < 6; ++s2) {
            const int j = j0 + s2;
            if (j < 22) {
                out[ob + (size_t)c_loc * 31680
                       + (size_t)((8 + i0r + r) * 22 + j)] = acc2[r][s2];
            }
        }
    }
}

extern "C" void kernel_launch(void* const* d_in, const int* in_sizes, int n_in,
                              void* d_out, int out_size, void* d_ws, size_t ws_size,
                              hipStream_t stream) {
    const float* x   = (const float*)d_in[0];
    const float* dx  = (const float*)d_in[1];
    const float* dy  = (const float*)d_in[2];
    const float* ls2 = (const float*)d_in[3];
    const float* ld  = (const float*)d_in[4];
    const float* lg  = (const float*)d_in[5];
    const float* dtp = (const float*)d_in[6];
    const float* ldt = (const float*)d_in[7];
    const float* lgt = (const float*)d_in[8];
    float* out = (float*)d_out;

    dim3 grid(16 * 30 * 8), block(256);
    hipLaunchKernelGGL(gst_kernel, grid, block, 0, stream,
                       x, dx, dy, ls2, ld, lg, dtp, ldt, lgt, out);
}

// Round 5
// 591.983 us; speedup vs baseline: 1.3299x; 1.0550x over previous
//
#include <hip/hip_runtime.h>
#include <math.h>

// GaussianSampleST fused kernel (fp32)
// x:(16,64,30,64,44)  out:(16,64,30,48,22)
// Block = (n, t_out, channel-group-of-8); grid = 16*30*8 = 3840, 256 threads.
// v5: LDS 25,728 B (t2s h-quartered [8][16][26]) -> 6 blocks/CU by LDS;
// GEMM1 j-split (2 lanes per x-row, 12-col slices w/ 2-col overlap; FxT
// duplicated [44][2][12] so both slices 16B-aligned) -> a[12] per thread,
// VGPR target <=100 -> 5 waves/SIMD.  GEMM1(q+1) issued in the same barrier
// region as GEMM2(q): x-load latency hides under LDS work.

#define EPS_ 1e-8f

__global__ __launch_bounds__(256) void gst_kernel(
    const float* __restrict__ x,
    const float* __restrict__ dx,  const float* __restrict__ dy,
    const float* __restrict__ ls2, const float* __restrict__ ld,
    const float* __restrict__ lg,
    const float* __restrict__ dtp, const float* __restrict__ ldt,
    const float* __restrict__ lgt,
    float* __restrict__ out)
{
    __shared__ float FyT[64][32];      // [h][i]  (Fy, pre-scaled by Ws*gamma)
    __shared__ float FxT2[44][2][12];  // [w][slot][jloc]; slot0=cols 0..11, slot1=cols 10..21
    __shared__ float t2s[8][16][26];   // [c][h-in-quarter][j], stride 26

    const int tid = threadIdx.x;
    int b = blockIdx.x;
    const int cg = b & 7; b >>= 3;
    const int tq = b % 30;
    const int n  = b / 30;

    // ---- temporal interpolation params (block-uniform) ----
    const float dtv     = tanhf(dtp[n]) * 15.f + 15.f;
    const float delta_t = expf(ldt[n]);
    const float gamma_t = 1.f / (1.f + expf(-lgt[n]));
    float mu_t = dtv + ((float)tq - 15.f) * delta_t;
    mu_t = mu_t / 29.f * 2.f - 1.f;
    const float iy  = ((mu_t + 1.f) * 30.f - 1.f) * 0.5f;
    const float iy0 = floorf(iy);
    const float w1  = iy - iy0;
    const int   i0  = (int)iy0;
    const int   i1  = i0 + 1;
    const float W0 = (i0 >= 0 && i0 < 30) ? 0.5f * gamma_t * (1.f - w1) : 0.f;
    const float W1 = (i1 >= 0 && i1 < 30) ? 0.5f * gamma_t * w1 : 0.f;
    const int t0 = min(max(i0, 0), 29);
    const int t1 = min(max(i1, 0), 29);

    // GEMM2 mapping (all 256 threads)
    const int c_loc = tid >> 5;        // 0..7  (also GEMM1's c)
    const int jt    = tid & 3;         // j-tile base 6*jt
    const int it    = (tid >> 2) & 7;  // i-tile base 4*it
    const int j0    = 6 * jt;
    const int i0r   = 4 * it;

    // GEMM1 mapping: tid bits: [0]=jh (j-slot), [4:1]=hl (row in quarter), [7:5]=c
    const int jh = tid & 1;            // slot: 0 -> cols 0..11, 1 -> cols 10..21
    const int hl = (tid >> 1) & 15;    // 0..15

    // ---- store zero pad rows early (independent of compute) ----
    const size_t ob =
        (((size_t)n * 64 + (size_t)(cg * 8)) * 30 + (size_t)tq) * 1056;
    for (int idx = tid; idx < 8 * 16 * 22; idx += 256) {
        const int c   = idx / 352;
        const int rem = idx % 352;
        const int r   = rem / 22;
        const int j   = rem % 22;
        const int ip  = (r < 8) ? r : (r + 32);
        out[ob + (size_t)c * 31680 + (size_t)(ip * 22 + j)] = 0.f;
    }

    float acc2[4][6];
#pragma unroll
    for (int r = 0; r < 4; ++r)
#pragma unroll
        for (int s2 = 0; s2 < 6; ++s2) acc2[r][s2] = 0.f;

    float a[12];   // GEMM1 result slice (lives across the GEMM2 it overlaps)

#pragma unroll 1
    for (int s = 0; s < 2; ++s) {
        const float Ws = s ? W1 : W0;
        const int   ts = s ? t1 : t0;
        if (Ws == 0.f) continue;          // block-uniform branch

        // ---- per-source attention params into LDS (all 256 lanes) ----
        const int nt = n * 30 + ts;
        const float sigma2 = expf(ls2[nt]);
        const float inv2s2 = 0.5f / sigma2;
        const float delta  = expf(ld[nt]);
        const float gamma  = 1.f / (1.f + expf(-lg[nt]));
        const float A      = Ws * gamma;

        if (tid < 128) {
            // Fy: row i = tid>>2 (0..31), quarter q = tid&3 covers h = 16q..16q+15
            const int i = tid >> 2, q = tid & 3;
            float pod = dy[nt] + 0.5f * (ts >= 1 ? dy[nt - 1] : 0.f)
                               + 0.5f * (ts >= 2 ? dy[nt - 2] : 0.f);
            const float mu = tanhf(pod) * 32.f + 32.f + ((float)i - 16.f) * delta;
            float e[16];
            float sum = 0.f;
#pragma unroll
            for (int k = 0; k < 16; ++k) {
                const float d = (float)(16 * q + k) - mu;
                e[k] = expf(-d * d * inv2s2);
                sum += e[k];
            }
            sum += __shfl_xor(sum, 1);
            sum += __shfl_xor(sum, 2);
            const float sc = A / fmaxf(sum, EPS_);
#pragma unroll
            for (int k = 0; k < 16; ++k)
                FyT[16 * q + k][i] = e[k] * sc;
        } else {
            // Fx: col j = (tid-128)>>2, quarter q covers w = 11q..11q+10
            const int tx = tid - 128;
            const int j = tx >> 2, q = tx & 3;
            float pod = dx[nt] + 0.5f * (ts >= 1 ? dx[nt - 1] : 0.f)
                               + 0.5f * (ts >= 2 ? dx[nt - 2] : 0.f);
            const float mu = tanhf(pod) * 22.f + 22.f + ((float)j - 11.f) * delta;
            float e[11];
            float sum = 0.f;
#pragma unroll
            for (int m = 0; m < 11; ++m) {
                const float d = (float)(11 * q + m) - mu;
                e[m] = expf(-d * d * inv2s2);
                sum += e[m];
            }
            sum += __shfl_xor(sum, 1);
            sum += __shfl_xor(sum, 2);
            const float sc = 1.f / fmaxf(sum, EPS_);
            if (j < 22) {
#pragma unroll
                for (int m = 0; m < 11; ++m) {
                    const float v = e[m] * sc;
                    const int   w = 11 * q + m;
                    if (j < 12)  FxT2[w][0][j]      = v;
                    if (j >= 10) FxT2[w][1][j - 10] = v;
                }
            }
        }
        __syncthreads();   // FyT/FxT2 ready (prior source fully drained by tail sync)

        // per-source x row base for this thread's channel
        const size_t xbase =
            ((((size_t)n * 64 + (size_t)(cg * 8 + c_loc)) * 30
              + (size_t)ts) * 64) * 44;

        // ---- GEMM1 for a quarter: a[0..11] = sum_w X[c][q16+hl][w] * Fx[w][jh-slice]
        auto gemm1 = [&](int q16) {
            const float4* xr =
                reinterpret_cast<const float4*>(x + xbase + (size_t)(q16 + hl) * 44);
#pragma unroll
            for (int j = 0; j < 12; ++j) a[j] = 0.f;
            float4 xc = xr[0], xn = xr[1];
#pragma unroll
            for (int wi = 0; wi < 11; ++wi) {
                const float4 xf = xr[(wi + 2 <= 10) ? (wi + 2) : 0];
                const float xav[4] = { xc.x, xc.y, xc.z, xc.w };
#pragma unroll
                for (int k = 0; k < 4; ++k) {
                    const float4* fp =
                        reinterpret_cast<const float4*>(&FxT2[4 * wi + k][jh][0]);
                    const float4 f0 = fp[0], f1 = fp[1], f2 = fp[2];
                    const float fv[12] = { f0.x, f0.y, f0.z, f0.w,
                                           f1.x, f1.y, f1.z, f1.w,
                                           f2.x, f2.y, f2.z, f2.w };
                    const float va = xav[k];
#pragma unroll
                    for (int j = 0; j < 12; ++j) a[j] += va * fv[j];
                }
                xc = xn; xn = xf;
            }
        };

        // ---- store a[] slice into t2s (floats jh*10 .. jh*10+11, plus pads)
        auto store_t2s = [&]() {
            float2* base = reinterpret_cast<float2*>(&t2s[c_loc][hl][0]);
            float2* dst  = base + jh * 5;          // float offset jh*10
#pragma unroll
            for (int p = 0; p < 6; ++p)
                dst[p] = make_float2(a[2 * p], a[2 * p + 1]);
            base[11 + jh] = make_float2(0.f, 0.f); // floats 22,23 / 24,25 zeroed
        };

        // ---- GEMM2 for a quarter: acc2 += Fy[q16+hp][i]^T * t2s[c][hp][j]
        auto gemm2 = [&](int q16) {
#pragma unroll 4
            for (int hp2 = 0; hp2 < 16; ++hp2) {
                const float4 fy =
                    *reinterpret_cast<const float4*>(&FyT[q16 + hp2][i0r]);
                const float2* tp =
                    reinterpret_cast<const float2*>(&t2s[c_loc][hp2][j0]);
                const float2 q0 = tp[0], q1 = tp[1], q2 = tp[2];
                const float fyv[4] = { fy.x, fy.y, fy.z, fy.w };
                const float tv[6]  = { q0.x, q0.y, q1.x, q1.y, q2.x, q2.y };
#pragma unroll
                for (int r = 0; r < 4; ++r)
#pragma unroll
                    for (int s2 = 0; s2 < 6; ++s2)
                        acc2[r][s2] += fyv[r] * tv[s2];
            }
        };

        // prologue: quarter 0
        gemm1(0);
        store_t2s();
        __syncthreads();   // t2s(0) visible

        // pipelined quarters: GEMM1(q+1) overlaps GEMM2(q) in one barrier region
#pragma unroll 1
        for (int q = 0; q < 4; ++q) {
            if (q < 3) gemm1((q + 1) * 16);   // regs only; x-loads fly under GEMM2
            gemm2(q * 16);
            __syncthreads();                  // all reads of t2s(q) done
            if (q < 3) {
                store_t2s();
                __syncthreads();              // t2s(q+1) visible
            }
        }
        // tail sync of q==3 protects FyT/FxT2 for next source's param phase
    }

    // ---- store main 32 rows ----
#pragma unroll
    for (int r = 0; r < 4; ++r) {
#pragma unroll
        for (int s2 = 0; s2 < 6; ++s2) {
            const int j = j0 + s2;
            if (j < 22) {
                out[ob + (size_t)c_loc * 31680
                       + (size_t)((8 + i0r + r) * 22 + j)] = acc2[r][s2];
            }
        }
    }
}

extern "C" void kernel_launch(void* const* d_in, const int* in_sizes, int n_in,
                              void* d_out, int out_size, void* d_ws, size_t ws_size,
                              hipStream_t stream) {
    const float* x   = (const float*)d_in[0];
    const float* dx  = (const float*)d_in[1];
    const float* dy  = (const float*)d_in[2];
    const float* ls2 = (const float*)d_in[3];
    const float* ld  = (const float*)d_in[4];
    const float* lg  = (const float*)d_in[5];
    const float* dtp = (const float*)d_in[6];
    const float* ldt = (const float*)d_in[7];
    const float* lgt = (const float*)d_in[8];
    float* out = (float*)d_out;

    dim3 grid(16 * 30 * 8), block(256);
    hipLaunchKernelGGL(gst_kernel, grid, block, 0, stream,
                       x, dx, dy, ls2, ld, lg, dtp, ldt, lgt, out);
}